// Round 17
// baseline (580.472 us; speedup 1.0000x reference)
//
#include <hip/hip_runtime.h>
#include <hip/hip_bf16.h>

using bf16   = __bf16;
using bf16x4 = __attribute__((ext_vector_type(4))) __bf16;
using bf16x8 = __attribute__((ext_vector_type(8))) __bf16;
using f32x4  = __attribute__((ext_vector_type(4))) float;

#define B_TOT 2048
#define NTOK  98
#define CDIM  192
#define NHEAD 6
#define HDIM  32
#define NWIN  512
#define NN    (NTOK*NTOK)            /* 9604 */
#define QKV_ELEMS ((size_t)B_TOT*NHEAD*NTOK*HDIM)  /* 38535168 */
#define NUNIT (B_TOT*NHEAD)          /* 12288 */
#define VSTRIDE 112                  /* padded n-stride of vT (16B-aligned rows) */
#define VUNIT  (HDIM*VSTRIDE)        /* 3584 elems per (b,h) unit */
#define MROWS 200704
#define SCALE 0.17677669529663687f   /* 32^-0.5 */

#define MFMA(a,b,c) __builtin_amdgcn_mfma_f32_16x16x32_bf16((a),(b),(c),0,0,0)

// async global->LDS, 16B per lane; LDS dest is wave-uniform base (+lane*16 by HW)
#define GLD16(gp, lp) __builtin_amdgcn_global_load_lds(                        \
    (const __attribute__((address_space(1))) void*)(gp),                       \
    (__attribute__((address_space(3))) void*)(lp), 16, 0, 0)

// ---------------------------------------------------------------------------
// bias[h][i][j] = rpb_table[rel_pos_index[i*98+j]][h]
// ---------------------------------------------------------------------------
__global__ void build_bias(const float* __restrict__ table,
                           const int* __restrict__ rel,
                           float* __restrict__ bias) {
    int t = blockIdx.x * 256 + threadIdx.x;
    if (t < NN) {
        int idx = rel[t];
        #pragma unroll
        for (int h = 0; h < NHEAD; ++h)
            bias[h * NN + t] = table[idx * NHEAD + h];
    }
}

// ---------------------------------------------------------------------------
// zero vT pad columns n=98..111 for every (unit, hd): 7 dwords per row.
// Must run before attn (pad bytes may be recycled f32 output = bf16 NaN risk).
// ---------------------------------------------------------------------------
__global__ void zero_vpad(bf16* __restrict__ vT) {
    int t = blockIdx.x * 256 + threadIdx.x;            // one dword each
    int total = NUNIT * HDIM * 7;
    for (; t < total; t += 2688 * 256) {
        int row = t / 7, d = t % 7;
        *(unsigned*)((char*)vT + (size_t)row * (VSTRIDE * 2) + 196 + d * 4) = 0u;
    }
}

// ---------------------------------------------------------------------------
// f32 -> bf16 weight converter with T2 row-XOR swizzle baked into storage
// (rows of length CDIM only — used for qkv_w and proj_w).
// ---------------------------------------------------------------------------
__global__ void conv_swz(const float* __restrict__ src, bf16* __restrict__ dst,
                         int nchunk) {
    int t = blockIdx.x * 256 + threadIdx.x;
    if (t < nchunk) {
        int row = t / 24, c = t % 24;
        const float* s = src + (size_t)row * CDIM + c * 8;
        bf16x8 o;
        #pragma unroll
        for (int e = 0; e < 8; ++e) o[e] = (bf16)s[e];
        *(bf16x8*)(dst + (size_t)row * CDIM + ((c ^ (row & 7)) << 3)) = o;
    }
}

// ---------------------------------------------------------------------------
// QKV GEMM v9 (unchanged from round 16): A from f32 x to regs, B
// double-buffered via global_load_lds, one barrier/chunk; V stored
// TRANSPOSED to vT[u][hd][VSTRIDE] (lives in d_out, dead until proj).
// ---------------------------------------------------------------------------
__global__ __launch_bounds__(256) void qkv_gemm(
    const float* __restrict__ x, const bf16* __restrict__ wb,
    const float* __restrict__ bvec,
    bf16* __restrict__ qdst, bf16* __restrict__ kdst, bf16* __restrict__ vT)
{
    __shared__ char Bs[2][24576];
    const int tid = threadIdx.x, lane = tid & 63, wv = tid >> 6;
    const int l15 = lane & 15, l16 = lane >> 4;
    const int m0 = blockIdx.x * 64;

    {
        const char* bsrc = (const char*)wb;
        #pragma unroll
        for (int j = 0; j < 6; ++j) {
            const int ch = wv * 6 + j;
            GLD16(bsrc + ch * 1024 + lane * 16, Bs[0] + ch * 1024);
        }
    }

    const int arow = wv * 16 + l15;
    const int grow = m0 + arow;
    const float* xr = x + (size_t)grow * CDIM + l16 * 8;
    bf16x8 af[6];
    #pragma unroll
    for (int ks = 0; ks < 6; ++ks) {
        float4 v0 = *(const float4*)(xr + ks * 32);
        float4 v1 = *(const float4*)(xr + ks * 32 + 4);
        bf16x8 a;
        a[0] = (bf16)v0.x; a[1] = (bf16)v0.y; a[2] = (bf16)v0.z; a[3] = (bf16)v0.w;
        a[4] = (bf16)v1.x; a[5] = (bf16)v1.y; a[6] = (bf16)v1.z; a[7] = (bf16)v1.w;
        af[ks] = a;
    }

    __syncthreads();

    const int gb = grow / NTOK, gn = grow % NTOK;
    const int rowoff = gb * 18816 + gn * 32;
    const f32x4 z4 = {0.f, 0.f, 0.f, 0.f};

    #pragma unroll
    for (int nc = 0; nc < 9; ++nc) {
        if (nc < 8) {
            const char* bsrc = (const char*)wb + (size_t)(nc + 1) * 24576;
            #pragma unroll
            for (int j = 0; j < 6; ++j) {
                const int ch = wv * 6 + j;
                GLD16(bsrc + ch * 1024 + lane * 16, Bs[(nc + 1) & 1] + ch * 1024);
            }
        }

        f32x4 acc[4];
        #pragma unroll
        for (int ct = 0; ct < 4; ++ct) acc[ct] = z4;

        #pragma unroll
        for (int ks = 0; ks < 6; ++ks) {
            #pragma unroll
            for (int ct = 0; ct < 4; ++ct) {
                const int brow = ct * 16 + l15;
                bf16x8 bf = *(const bf16x8*)(Bs[nc & 1] + brow * 384
                                             + (((ks * 4 + l16) ^ (brow & 7)) << 4));
                acc[ct] = MFMA(bf, af[ks], acc[ct]);
            }
        }

        #pragma unroll
        for (int ct = 0; ct < 4; ++ct) {
            const int g0    = nc * 64 + ct * 16;   // compile-time
            const int which = g0 / CDIM;
            const int cm    = g0 % CDIM;
            const int h     = cm >> 5, hd0 = cm & 31;
            const float4 bvf = *(const float4*)(bvec + g0 + l16 * 4);
            if (which == 2) {
                // transposed store: vT[(gb*6+h)*VUNIT + hd*VSTRIDE + gn]
                bf16* vp = vT + (size_t)(gb * NHEAD + h) * VUNIT
                         + (hd0 + l16 * 4) * VSTRIDE + gn;
                #pragma unroll
                for (int r = 0; r < 4; ++r)
                    vp[r * VSTRIDE] = (bf16)(acc[ct][r] + ((const float*)&bvf)[r]);
            } else {
                bf16x4 s;
                #pragma unroll
                for (int r = 0; r < 4; ++r) {
                    float v = acc[ct][r] + ((const float*)&bvf)[r];
                    if (which == 0) v *= SCALE;
                    s[r] = (bf16)v;
                }
                bf16* dp = (which == 0) ? qdst : kdst;
                *(bf16x4*)(dp + rowoff + h * 3136 + hd0 + l16 * 4) = s;
            }
        }
        __syncthreads();
    }
}

// ---------------------------------------------------------------------------
// Fused attention v14-lean: zero-barrier wave-per-unit with MINIMAL residency
// footprint. vs v13: K fragments NOT hoisted (reloaded per i-tile from
// L1/L2-resident k tile) and __launch_bounds__(256,6) forces the register
// allocator toward >=6 waves/SIMD (<=~85 VGPR). LDS = 4KB P + 64B invS per
// wave. This is the clean occupancy/MLP experiment: many resident waves,
// each with many independent loads in flight.
// ---------------------------------------------------------------------------
__global__ __launch_bounds__(256, 6) void attn_fused(
    const bf16* __restrict__ q, const bf16* __restrict__ k,
    const bf16* __restrict__ vT,
    const float* __restrict__ mask, const float* __restrict__ bias,
    bf16* __restrict__ ao)
{
    __shared__ char lds[4 * 4096 + 4 * 64];
    const int tid = threadIdx.x, lane = tid & 63, wv = tid >> 6;
    const int l15 = lane & 15, l16 = lane >> 4;
    char*  P    = lds + wv * 4096;                  // 16 x 128 bf16, swizzled
    float* invS = (float*)(lds + 16384 + wv * 64);  // 16 floats

    const int u = blockIdx.x * 4 + wv;              // unit id: (b*6+h)
    const int b = u / NHEAD, h = u - b * NHEAD;
    const int w = b & (NWIN - 1);
    const size_t bho = (size_t)u * 3136;
    const bf16* vu = vT + (size_t)u * VUNIT;
    const bf16* ku = k + bho;

    // zero pads: P rows 0..15 cols 112..127 (64 x 8B = 1/lane)
    {
        int zr = lane >> 2;
        int zc = 112 + (lane & 3) * 4;
        *(unsigned long long*)(P + zr * 256 + (((zc >> 3) ^ (zr & 7)) << 4)
                               + ((zc & 7) << 1)) = 0ull;
    }

    const float* mrow = mask + (size_t)w * NN;
    const float* brow = bias + (size_t)h * NN;
    bf16* dst = ao + (size_t)b * NTOK * CDIM;
    const f32x4 z4 = {0.f, 0.f, 0.f, 0.f};

    const int kroff = l16 * 8;        // k fragment column offset
    int krow[7];
    #pragma unroll
    for (int jt = 0; jt < 7; ++jt) {
        int kr = jt * 16 + l15; if (kr > 97) kr = 97;
        krow[jt] = kr * HDIM + kroff;
    }

    #pragma unroll 1
    for (int it = 0; it < 7; ++it) {
        // QK^T for this i-tile; kf reloaded per tile (L1/L2-resident, keeps
        // VGPR low so more waves stay resident)
        int qrow = it * 16 + l15; if (qrow > 97) qrow = 97;
        const bf16x8 qf = *(const bf16x8*)(q + bho + qrow * HDIM + l16 * 8);
        f32x4 acc[7];
        #pragma unroll
        for (int jt = 0; jt < 7; ++jt) {
            bf16x8 kf = *(const bf16x8*)(ku + krow[jt]);
            acc[jt] = MFMA(qf, kf, z4);
        }

        // softmax (no max-sub; deferred normalization). Row i = it*16+l16*4+r,
        // col j = jt*16+l15 (16 consecutive floats per load -> coalesced).
        #pragma unroll
        for (int r = 0; r < 4; ++r) {
            int i = it * 16 + l16 * 4 + r; if (i > 97) i = 97;
            float s = 0.f;
            #pragma unroll
            for (int jt = 0; jt < 7; ++jt) {
                int j = jt * 16 + l15;
                float mbv = (j < NTOK) ? (mrow[i * NTOK + j] + brow[i * NTOK + j])
                                       : -__builtin_inff();
                float e = __expf(acc[jt][r] + mbv);
                acc[jt][r] = e; s += e;
            }
            s += __shfl_xor(s, 1, 16);
            s += __shfl_xor(s, 2, 16);
            s += __shfl_xor(s, 4, 16);
            s += __shfl_xor(s, 8, 16);
            if (l15 == 0) invS[l16 * 4 + r] = 1.f / s;
        }

        // write unnormalized P (wave-private; within-wave lgkmcnt ordering)
        #pragma unroll
        for (int jt = 0; jt < 7; ++jt) {
            #pragma unroll
            for (int r = 0; r < 4; ++r) {
                int row = l16 * 4 + r;
                int j = jt * 16 + l15;
                *(bf16*)(P + row * 256 + (((j >> 3) ^ (row & 7)) << 4) + ((j & 7) << 1))
                    = (bf16)acc[jt][r];
            }
        }

        // PV: pf from wave-private P LDS; V^T fragments direct from global
        // (VSTRIDE=112 -> 16B-aligned rows). Pad j=98..111 zeroed; j=112..127
        // reads spill into next hd row (finite) x P=0 -> 0.
        f32x4 o0 = z4, o1 = z4;
        #pragma unroll
        for (int ks = 0; ks < 4; ++ks) {
            int kchunk = ks * 4 + l16;
            bf16x8 pf = *(const bf16x8*)(P + l15 * 256 + ((kchunk ^ (l15 & 7)) << 4));
            bf16x8 v0 = *(const bf16x8*)(vu + l15 * VSTRIDE + ks * 32 + l16 * 8);
            bf16x8 v1 = *(const bf16x8*)(vu + (16 + l15) * VSTRIDE + ks * 32 + l16 * 8);
            o0 = MFMA(v0, pf, o0);
            o1 = MFMA(v1, pf, o1);
        }

        {
            int row = it * 16 + l15;
            if (row < NTOK) {
                float inv = invS[l15];
                bf16x4 s0, s1;
                #pragma unroll
                for (int r = 0; r < 4; ++r) {
                    s0[r] = (bf16)(o0[r] * inv);
                    s1[r] = (bf16)(o1[r] * inv);
                }
                // swizzled store keyed on GLOBAL flat row (b*98+row):
                const int swr = (b * NTOK + row) & 7;
                const int c0 = h * 4 + (l16 >> 1);
                const int c1 = c0 + 2;
                const int wi = (l16 & 1) << 2;
                *(bf16x4*)(dst + (size_t)row * CDIM + (((c0 ^ swr) << 3) | wi)) = s0;
                *(bf16x4*)(dst + (size_t)row * CDIM + (((c1 ^ swr) << 3) | wi)) = s1;
            }
        }
    }
}

// ---------------------------------------------------------------------------
// Proj GEMM v7 (unchanged from round 9).
// ---------------------------------------------------------------------------
__global__ __launch_bounds__(256) void proj_gemm(
    const bf16* __restrict__ ao, const bf16* __restrict__ wb,
    const float* __restrict__ bvec, float* __restrict__ out)
{
    __shared__ char As[24576];
    __shared__ char Bs[2][24576];
    const int tid = threadIdx.x, lane = tid & 63, wv = tid >> 6;
    const int l15 = lane & 15, l16 = lane >> 4;
    const int m0 = blockIdx.x * 64;

    {
        const char* asrc = (const char*)ao + (size_t)m0 * 384;
        const char* bsrc = (const char*)wb;
        #pragma unroll
        for (int j = 0; j < 6; ++j) {
            const int ch = wv * 6 + j;
            GLD16(asrc + ch * 1024 + lane * 16, As + ch * 1024);
            GLD16(bsrc + ch * 1024 + lane * 16, Bs[0] + ch * 1024);
        }
    }
    __syncthreads();

    const int arow = wv * 16 + l15;
    bf16x8 af[6];
    #pragma unroll
    for (int ks = 0; ks < 6; ++ks)
        af[ks] = *(const bf16x8*)(As + arow * 384 + (((ks * 4 + l16) ^ (arow & 7)) << 4));

    const size_t orow = (size_t)(m0 + arow) * CDIM;
    const f32x4 z4 = {0.f, 0.f, 0.f, 0.f};

    #pragma unroll
    for (int nc = 0; nc < 3; ++nc) {
        if (nc < 2) {
            const char* bsrc = (const char*)wb + (size_t)(nc + 1) * 24576;
            #pragma unroll
            for (int j = 0; j < 6; ++j) {
                const int ch = wv * 6 + j;
                GLD16(bsrc + ch * 1024 + lane * 16, Bs[(nc + 1) & 1] + ch * 1024);
            }
        }

        f32x4 acc[4];
        #pragma unroll
        for (int ct = 0; ct < 4; ++ct) acc[ct] = z4;

        #pragma unroll
        for (int ks = 0; ks < 6; ++ks) {
            #pragma unroll
            for (int ct = 0; ct < 4; ++ct) {
                const int brow = ct * 16 + l15;
                bf16x8 bf = *(const bf16x8*)(Bs[nc & 1] + brow * 384
                                             + (((ks * 4 + l16) ^ (brow & 7)) << 4));
                acc[ct] = MFMA(bf, af[ks], acc[ct]);
            }
        }

        #pragma unroll
        for (int ct = 0; ct < 4; ++ct) {
            const int g0 = nc * 64 + ct * 16;
            const float4 bvf = *(const float4*)(bvec + g0 + l16 * 4);
            f32x4 s;
            #pragma unroll
            for (int r = 0; r < 4; ++r)
                s[r] = acc[ct][r] + ((const float*)&bvf)[r];
            *(f32x4*)(out + orow + g0 + l16 * 4) = s;
        }
        __syncthreads();
    }
}

// ---------------------------------------------------------------------------
extern "C" void kernel_launch(void* const* d_in, const int* in_sizes, int n_in,
                              void* d_out, int out_size, void* d_ws, size_t ws_size,
                              hipStream_t stream)
{
    (void)in_sizes; (void)n_in; (void)out_size; (void)ws_size;
    const float* x      = (const float*)d_in[0];
    const float* mask   = (const float*)d_in[1];
    const float* qkv_w  = (const float*)d_in[2];
    const float* qkv_b  = (const float*)d_in[3];
    const float* proj_w = (const float*)d_in[4];
    const float* proj_b = (const float*)d_in[5];
    const float* rpb    = (const float*)d_in[6];
    const int*   rel    = (const int*)d_in[7];
    float* out = (float*)d_out;

    char* ws = (char*)d_ws;
    bf16* qb = (bf16*)ws;
    bf16* kb = qb + QKV_ELEMS;
    size_t off = 2 * QKV_ELEMS * sizeof(bf16);
    float* bias = (float*)(ws + off);
    off += ((size_t)NHEAD * NN * 4 + 255) / 256 * 256;
    bf16* ao = (bf16*)(ws + off);
    // vT lives in d_out (154MB f32 out buffer >= 88MB; dead until proj writes)
    bf16* vT  = (bf16*)d_out;
    // overlapped weight buffers:
    bf16* qwb = ao;               // swizzled qkv_w; dead before attn writes ao
    bf16* pwb = qb;               // swizzled proj_w; written after attn (qb dead)

    zero_vpad<<<2688, 256, 0, stream>>>(vT);
    build_bias<<<(NN + 255) / 256, 256, 0, stream>>>(rpb, rel, bias);
    conv_swz<<<(576 * 24 + 255) / 256, 256, 0, stream>>>(qkv_w, qwb, 576 * 24);
    qkv_gemm<<<MROWS / 64, 256, 0, stream>>>(x, qwb, qkv_b, qb, kb, vT);
    attn_fused<<<NUNIT / 4, 256, 0, stream>>>(qb, kb, vT, mask, bias, ao);
    conv_swz<<<(192 * 24 + 255) / 256, 256, 0, stream>>>(proj_w, pwb, 192 * 24);
    proj_gemm<<<MROWS / 64, 256, 0, stream>>>(ao, pwb, proj_b, out);
}

// Round 18
// 329.873 us; speedup vs baseline: 1.7597x; 1.7597x over previous
//
#include <hip/hip_runtime.h>
#include <hip/hip_bf16.h>

using bf16   = __bf16;
using bf16x4 = __attribute__((ext_vector_type(4))) __bf16;
using bf16x8 = __attribute__((ext_vector_type(8))) __bf16;
using f32x4  = __attribute__((ext_vector_type(4))) float;

#define B_TOT 2048
#define NTOK  98
#define CDIM  192
#define NHEAD 6
#define HDIM  32
#define NWIN  512
#define NN    (NTOK*NTOK)            /* 9604 */
#define QKV_ELEMS ((size_t)B_TOT*NHEAD*NTOK*HDIM)  /* 38535168 */
#define MROWS 200704
#define SCALE 0.17677669529663687f   /* 32^-0.5 */

#define MFMA(a,b,c) __builtin_amdgcn_mfma_f32_16x16x32_bf16((a),(b),(c),0,0,0)

// async global->LDS, 16B per lane; LDS dest is wave-uniform base (+lane*16 by HW)
#define GLD16(gp, lp) __builtin_amdgcn_global_load_lds(                        \
    (const __attribute__((address_space(1))) void*)(gp),                       \
    (__attribute__((address_space(3))) void*)(lp), 16, 0, 0)

// ---------------------------------------------------------------------------
// bias[h][i][j] = rpb_table[rel_pos_index[i*98+j]][h]
// ---------------------------------------------------------------------------
__global__ void build_bias(const float* __restrict__ table,
                           const int* __restrict__ rel,
                           float* __restrict__ bias) {
    int t = blockIdx.x * 256 + threadIdx.x;
    if (t < NN) {
        int idx = rel[t];
        #pragma unroll
        for (int h = 0; h < NHEAD; ++h)
            bias[h * NN + t] = table[idx * NHEAD + h];
    }
}

// ---------------------------------------------------------------------------
// f32 -> bf16 weight converter with T2 row-XOR swizzle baked into storage
// (rows of length CDIM only — used for qkv_w and proj_w).
// ---------------------------------------------------------------------------
__global__ void conv_swz(const float* __restrict__ src, bf16* __restrict__ dst,
                         int nchunk) {
    int t = blockIdx.x * 256 + threadIdx.x;
    if (t < nchunk) {
        int row = t / 24, c = t % 24;
        const float* s = src + (size_t)row * CDIM + c * 8;
        bf16x8 o;
        #pragma unroll
        for (int e = 0; e < 8; ++e) o[e] = (bf16)s[e];
        *(bf16x8*)(dst + (size_t)row * CDIM + ((c ^ (row & 7)) << 3)) = o;
    }
}

// ---------------------------------------------------------------------------
// QKV GEMM v8 (round 11 version): A from f32 x direct to regs, B
// double-buffered in LDS via global_load_lds, one barrier per chunk.
// q/k/v stored [b][h][n][hd] bf16.
// ---------------------------------------------------------------------------
__global__ __launch_bounds__(256) void qkv_gemm(
    const float* __restrict__ x, const bf16* __restrict__ wb,
    const float* __restrict__ bvec,
    bf16* __restrict__ qdst, bf16* __restrict__ kdst, bf16* __restrict__ vdst)
{
    __shared__ char Bs[2][24576];
    const int tid = threadIdx.x, lane = tid & 63, wv = tid >> 6;
    const int l15 = lane & 15, l16 = lane >> 4;
    const int m0 = blockIdx.x * 64;

    {
        const char* bsrc = (const char*)wb;
        #pragma unroll
        for (int j = 0; j < 6; ++j) {
            const int ch = wv * 6 + j;
            GLD16(bsrc + ch * 1024 + lane * 16, Bs[0] + ch * 1024);
        }
    }

    const int arow = wv * 16 + l15;
    const int grow = m0 + arow;
    const float* xr = x + (size_t)grow * CDIM + l16 * 8;
    bf16x8 af[6];
    #pragma unroll
    for (int ks = 0; ks < 6; ++ks) {
        float4 v0 = *(const float4*)(xr + ks * 32);
        float4 v1 = *(const float4*)(xr + ks * 32 + 4);
        bf16x8 a;
        a[0] = (bf16)v0.x; a[1] = (bf16)v0.y; a[2] = (bf16)v0.z; a[3] = (bf16)v0.w;
        a[4] = (bf16)v1.x; a[5] = (bf16)v1.y; a[6] = (bf16)v1.z; a[7] = (bf16)v1.w;
        af[ks] = a;
    }

    __syncthreads();

    const int rowoff = (grow / NTOK) * 18816 + (grow % NTOK) * 32;
    const f32x4 z4 = {0.f, 0.f, 0.f, 0.f};

    #pragma unroll
    for (int nc = 0; nc < 9; ++nc) {
        if (nc < 8) {
            const char* bsrc = (const char*)wb + (size_t)(nc + 1) * 24576;
            #pragma unroll
            for (int j = 0; j < 6; ++j) {
                const int ch = wv * 6 + j;
                GLD16(bsrc + ch * 1024 + lane * 16, Bs[(nc + 1) & 1] + ch * 1024);
            }
        }

        f32x4 acc[4];
        #pragma unroll
        for (int ct = 0; ct < 4; ++ct) acc[ct] = z4;

        #pragma unroll
        for (int ks = 0; ks < 6; ++ks) {
            #pragma unroll
            for (int ct = 0; ct < 4; ++ct) {
                const int brow = ct * 16 + l15;
                bf16x8 bf = *(const bf16x8*)(Bs[nc & 1] + brow * 384
                                             + (((ks * 4 + l16) ^ (brow & 7)) << 4));
                acc[ct] = MFMA(bf, af[ks], acc[ct]);
            }
        }

        #pragma unroll
        for (int ct = 0; ct < 4; ++ct) {
            const int g0    = nc * 64 + ct * 16;
            const int which = g0 / CDIM;
            const int cm    = g0 % CDIM;
            const int h     = cm >> 5, hd0 = cm & 31;
            const float4 bvf = *(const float4*)(bvec + g0 + l16 * 4);
            bf16x4 s;
            #pragma unroll
            for (int r = 0; r < 4; ++r) {
                float v = acc[ct][r] + ((const float*)&bvf)[r];
                if (which == 0) v *= SCALE;
                s[r] = (bf16)v;
            }
            bf16* dp = (which == 0) ? qdst : (which == 1) ? kdst : vdst;
            *(bf16x4*)(dp + rowoff + h * 3136 + hd0 + l16 * 4) = s;
        }
        __syncthreads();
    }
}

// ---------------------------------------------------------------------------
// Fused attention v12+T5: zero-barrier wave-independent (round 15 version)
// with s_setprio(1) wrapped around the QK and PV MFMA clusters. Mechanism
// (m191): waves at different phases on a CU — scheduler favors the MFMA-
// issuing wave over load-issuing waves. Applies to this shape (independent
// 1-wave units), NOT to lockstep GEMMs (m190).
// ---------------------------------------------------------------------------
__global__ __launch_bounds__(256) void attn_fused(
    const bf16* __restrict__ q, const bf16* __restrict__ k,
    const bf16* __restrict__ v,
    const float* __restrict__ mask, const float* __restrict__ bias,
    bf16* __restrict__ ao)
{
    __shared__ char lds[4 * 8192 + 4 * 4096 + 4 * 64];
    const int tid = threadIdx.x, lane = tid & 63, wv = tid >> 6;
    const int l15 = lane & 15, l16 = lane >> 4;
    char*  Vt   = lds + wv * 8192;                  // 32 x 128 bf16, swizzled
    char*  P    = lds + 32768 + wv * 4096;          // 16 x 128 bf16, swizzled
    float* invS = (float*)(lds + 49152 + wv * 64);  // 16 floats

    const int u = blockIdx.x * 4 + wv;              // unit id: (b*6+h)
    const int b = u / NHEAD, h = u - b * NHEAD;
    const int w = b & (NWIN - 1);
    const size_t bho = (size_t)u * 3136;

    // ---- issue V loads first (7 chunks to regs; oldest in flight) ----
    bf16x8 vvv[7];
    #pragma unroll
    for (int t = 0; t < 7; ++t) {
        int idx = t * 64 + lane;
        int n = idx >> 2; if (n > 97) n = 97;       // clamped (dup loads benign)
        int hd0 = (idx & 3) * 8;
        vvv[t] = *(const bf16x8*)(v + bho + n * 32 + hd0);
    }

    // ---- K fragments hoisted (reused by all 7 i-tiles) ----
    bf16x8 kf[7];
    #pragma unroll
    for (int jt = 0; jt < 7; ++jt) {
        int kr = jt * 16 + l15; if (kr > 97) kr = 97;
        kf[jt] = *(const bf16x8*)(k + bho + kr * HDIM + l16 * 8);
    }

    // ---- stage V^T into wave-private LDS (transpose) ----
    #pragma unroll
    for (int t = 0; t < 7; ++t) {
        int idx = t * 64 + lane;
        if (idx < 392) {
            int n = idx >> 2, hd0 = (idx & 3) * 8;
            #pragma unroll
            for (int e = 0; e < 8; ++e) {
                int hd = hd0 + e;
                *(bf16*)(Vt + hd * 256 + (((n >> 3) ^ (hd & 7)) << 4) + ((n & 7) << 1))
                    = vvv[t][e];
            }
        }
    }
    // zero pads: Vt cols 98..127 (960 elems = 15/lane)
    #pragma unroll
    for (int t = 0; t < 15; ++t) {
        int idx = t * 64 + lane;
        int hd = idx / 30, n = 98 + idx % 30;
        *(bf16*)(Vt + hd * 256 + (((n >> 3) ^ (hd & 7)) << 4) + ((n & 7) << 1)) = (bf16)0.f;
    }
    // zero pads: P rows 0..15 cols 112..127 (64 x 8B = 1/lane)
    {
        int zr = lane >> 2;
        int zc = 112 + (lane & 3) * 4;
        *(unsigned long long*)(P + zr * 256 + (((zc >> 3) ^ (zr & 7)) << 4)
                               + ((zc & 7) << 1)) = 0ull;
    }

    const float* mrow = mask + (size_t)w * NN;
    const float* brow = bias + (size_t)h * NN;
    bf16* dst = ao + (size_t)b * NTOK * CDIM;
    const f32x4 z4 = {0.f, 0.f, 0.f, 0.f};

    #pragma unroll 1
    for (int it = 0; it < 7; ++it) {
        // QK^T for this i-tile
        int qrow = it * 16 + l15; if (qrow > 97) qrow = 97;
        const bf16x8 qf = *(const bf16x8*)(q + bho + qrow * HDIM + l16 * 8);
        f32x4 acc[7];
        __builtin_amdgcn_s_setprio(1);
        #pragma unroll
        for (int jt = 0; jt < 7; ++jt)
            acc[jt] = MFMA(qf, kf[jt], z4);
        __builtin_amdgcn_s_setprio(0);

        // softmax (no max-sub; deferred normalization). Row i = it*16+l16*4+r,
        // col j = jt*16+l15 (16 consecutive floats per load -> coalesced).
        #pragma unroll
        for (int r = 0; r < 4; ++r) {
            int i = it * 16 + l16 * 4 + r; if (i > 97) i = 97;
            float s = 0.f;
            #pragma unroll
            for (int jt = 0; jt < 7; ++jt) {
                int j = jt * 16 + l15;
                float mbv = (j < NTOK) ? (mrow[i * NTOK + j] + brow[i * NTOK + j])
                                       : -__builtin_inff();
                float e = __expf(acc[jt][r] + mbv);
                acc[jt][r] = e; s += e;
            }
            s += __shfl_xor(s, 1, 16);
            s += __shfl_xor(s, 2, 16);
            s += __shfl_xor(s, 4, 16);
            s += __shfl_xor(s, 8, 16);
            if (l15 == 0) invS[l16 * 4 + r] = 1.f / s;
        }

        // write unnormalized P (wave-private; within-wave lgkmcnt ordering)
        #pragma unroll
        for (int jt = 0; jt < 7; ++jt) {
            #pragma unroll
            for (int r = 0; r < 4; ++r) {
                int row = l16 * 4 + r;
                int j = jt * 16 + l15;
                *(bf16*)(P + row * 256 + (((j >> 3) ^ (row & 7)) << 4) + ((j & 7) << 1))
                    = (bf16)acc[jt][r];
            }
        }

        // PV (operand-swapped): lane row = l15 (tile-local), cols hd = l16*4+r (+16)
        f32x4 o0 = z4, o1 = z4;
        __builtin_amdgcn_s_setprio(1);
        #pragma unroll
        for (int ks = 0; ks < 4; ++ks) {
            int kchunk = ks * 4 + l16;
            bf16x8 pf = *(const bf16x8*)(P + l15 * 256 + ((kchunk ^ (l15 & 7)) << 4));
            bf16x8 v0 = *(const bf16x8*)(Vt + l15 * 256 + ((kchunk ^ (l15 & 7)) << 4));
            bf16x8 v1 = *(const bf16x8*)(Vt + (16 + l15) * 256 + ((kchunk ^ (l15 & 7)) << 4));
            o0 = MFMA(v0, pf, o0);
            o1 = MFMA(v1, pf, o1);
        }
        __builtin_amdgcn_s_setprio(0);

        {
            int row = it * 16 + l15;
            if (row < NTOK) {
                float inv = invS[l15];
                bf16x4 s0, s1;
                #pragma unroll
                for (int r = 0; r < 4; ++r) {
                    s0[r] = (bf16)(o0[r] * inv);
                    s1[r] = (bf16)(o1[r] * inv);
                }
                // swizzled store keyed on GLOBAL flat row (b*98+row):
                const int swr = (b * NTOK + row) & 7;
                const int c0 = h * 4 + (l16 >> 1);
                const int c1 = c0 + 2;
                const int wi = (l16 & 1) << 2;
                *(bf16x4*)(dst + (size_t)row * CDIM + (((c0 ^ swr) << 3) | wi)) = s0;
                *(bf16x4*)(dst + (size_t)row * CDIM + (((c1 ^ swr) << 3) | wi)) = s1;
            }
        }
    }
}

// ---------------------------------------------------------------------------
// Proj GEMM v7 (unchanged from round 9).
// ---------------------------------------------------------------------------
__global__ __launch_bounds__(256) void proj_gemm(
    const bf16* __restrict__ ao, const bf16* __restrict__ wb,
    const float* __restrict__ bvec, float* __restrict__ out)
{
    __shared__ char As[24576];
    __shared__ char Bs[2][24576];
    const int tid = threadIdx.x, lane = tid & 63, wv = tid >> 6;
    const int l15 = lane & 15, l16 = lane >> 4;
    const int m0 = blockIdx.x * 64;

    {
        const char* asrc = (const char*)ao + (size_t)m0 * 384;
        const char* bsrc = (const char*)wb;
        #pragma unroll
        for (int j = 0; j < 6; ++j) {
            const int ch = wv * 6 + j;
            GLD16(asrc + ch * 1024 + lane * 16, As + ch * 1024);
            GLD16(bsrc + ch * 1024 + lane * 16, Bs[0] + ch * 1024);
        }
    }
    __syncthreads();

    const int arow = wv * 16 + l15;
    bf16x8 af[6];
    #pragma unroll
    for (int ks = 0; ks < 6; ++ks)
        af[ks] = *(const bf16x8*)(As + arow * 384 + (((ks * 4 + l16) ^ (arow & 7)) << 4));

    const size_t orow = (size_t)(m0 + arow) * CDIM;
    const f32x4 z4 = {0.f, 0.f, 0.f, 0.f};

    #pragma unroll
    for (int nc = 0; nc < 3; ++nc) {
        if (nc < 2) {
            const char* bsrc = (const char*)wb + (size_t)(nc + 1) * 24576;
            #pragma unroll
            for (int j = 0; j < 6; ++j) {
                const int ch = wv * 6 + j;
                GLD16(bsrc + ch * 1024 + lane * 16, Bs[(nc + 1) & 1] + ch * 1024);
            }
        }

        f32x4 acc[4];
        #pragma unroll
        for (int ct = 0; ct < 4; ++ct) acc[ct] = z4;

        #pragma unroll
        for (int ks = 0; ks < 6; ++ks) {
            #pragma unroll
            for (int ct = 0; ct < 4; ++ct) {
                const int brow = ct * 16 + l15;
                bf16x8 bf = *(const bf16x8*)(Bs[nc & 1] + brow * 384
                                             + (((ks * 4 + l16) ^ (brow & 7)) << 4));
                acc[ct] = MFMA(bf, af[ks], acc[ct]);
            }
        }

        #pragma unroll
        for (int ct = 0; ct < 4; ++ct) {
            const int g0 = nc * 64 + ct * 16;
            const float4 bvf = *(const float4*)(bvec + g0 + l16 * 4);
            f32x4 s;
            #pragma unroll
            for (int r = 0; r < 4; ++r)
                s[r] = acc[ct][r] + ((const float*)&bvf)[r];
            *(f32x4*)(out + orow + g0 + l16 * 4) = s;
        }
        __syncthreads();
    }
}

// ---------------------------------------------------------------------------
extern "C" void kernel_launch(void* const* d_in, const int* in_sizes, int n_in,
                              void* d_out, int out_size, void* d_ws, size_t ws_size,
                              hipStream_t stream)
{
    (void)in_sizes; (void)n_in; (void)out_size; (void)ws_size;
    const float* x      = (const float*)d_in[0];
    const float* mask   = (const float*)d_in[1];
    const float* qkv_w  = (const float*)d_in[2];
    const float* qkv_b  = (const float*)d_in[3];
    const float* proj_w = (const float*)d_in[4];
    const float* proj_b = (const float*)d_in[5];
    const float* rpb    = (const float*)d_in[6];
    const int*   rel    = (const int*)d_in[7];
    float* out = (float*)d_out;

    char* ws = (char*)d_ws;
    bf16* qb = (bf16*)ws;
    bf16* kb = qb + QKV_ELEMS;
    bf16* vb = kb + QKV_ELEMS;
    size_t off = 3 * QKV_ELEMS * sizeof(bf16);
    float* bias = (float*)(ws + off);
    off += ((size_t)NHEAD * NN * 4 + 255) / 256 * 256;
    bf16* ao = (bf16*)(ws + off);
    // overlapped weight buffers:
    bf16* qwb = ao;               // swizzled qkv_w; dead before attn writes ao
    bf16* pwb = qb;               // swizzled proj_w; written after attn (qb dead)

    build_bias<<<(NN + 255) / 256, 256, 0, stream>>>(rpb, rel, bias);
    conv_swz<<<(576 * 24 + 255) / 256, 256, 0, stream>>>(qkv_w, qwb, 576 * 24);
    qkv_gemm<<<MROWS / 64, 256, 0, stream>>>(x, qwb, qkv_b, qb, kb, vb);
    attn_fused<<<(B_TOT * NHEAD) / 4, 256, 0, stream>>>(qb, kb, vb, mask, bias, ao);
    conv_swz<<<(192 * 24 + 255) / 256, 256, 0, stream>>>(proj_w, pwb, 192 * 24);
    proj_gemm<<<MROWS / 64, 256, 0, stream>>>(ao, pwb, proj_b, out);
}